// Round 8
// baseline (510.285 us; speedup 1.0000x reference)
//
#include <hip/hip_runtime.h>
#include <hip/hip_bf16.h>

#define D_MODEL 1024
#define NHEAD   16
#define DK      64
#define SEQ     2048
#define BATCH   2

typedef __attribute__((ext_vector_type(8))) short bf16x8;   // 8 bf16 = 4 VGPR
typedef __attribute__((ext_vector_type(4))) float f32x4;

static __device__ __forceinline__ ushort f2bf(float f) {
  union { float f; unsigned u; } x; x.f = f;
  unsigned r = x.u + 0x7FFF + ((x.u >> 16) & 1);   // round-to-nearest-even
  return (ushort)(r >> 16);
}
static __device__ __forceinline__ float bf2f(ushort b) {
  union { unsigned u; float f; } x; x.u = ((unsigned)b) << 16;
  return x.f;
}

// Load one 8-element bf16 chunk from either an fp32 or a bf16 source.
template<bool F32>
static __device__ __forceinline__ bf16x8 load_chunk(const void* base, size_t eoff) {
  if constexpr (F32) {
    const float* p = (const float*)base + eoff;
    float4 a = *(const float4*)p;
    float4 b = *(const float4*)(p + 4);
    bf16x8 o;
    o[0] = (short)f2bf(a.x); o[1] = (short)f2bf(a.y);
    o[2] = (short)f2bf(a.z); o[3] = (short)f2bf(a.w);
    o[4] = (short)f2bf(b.x); o[5] = (short)f2bf(b.y);
    o[6] = (short)f2bf(b.z); o[7] = (short)f2bf(b.w);
    return o;
  } else {
    return *(const bf16x8*)((const ushort*)base + eoff);
  }
}

// ---------------- bf16 MFMA GEMM: C = A @ B^T + bias ---------------- (as R7)
template<int MODE, bool AF32, bool BF32>
__global__ __launch_bounds__(512) void gemm_bf16(
    const void* __restrict__ A, const void* __restrict__ B,
    const float* __restrict__ bias, void* __restrict__ C,
    int M, int N, int K, float outScale)
{
  __shared__ __align__(16) ushort At[2][128 * 32];
  __shared__ __align__(16) ushort Bt[2][128 * 32];
  const int tid = threadIdx.x;
  const int lane = tid & 63, wave = tid >> 6;
  const int wm = wave >> 1, wn = wave & 1;
  const int m0 = blockIdx.y * 128, n0 = blockIdx.x * 128;
  const int row = tid >> 2, kc = tid & 3;
  const size_t aoff = (size_t)(m0 + row) * K + kc * 8;
  const size_t boff = (size_t)(n0 + row) * K + kc * 8;
  const int lchunk = (kc * 128 + row) * 8;

  bf16x8 ra = load_chunk<AF32>(A, aoff);
  bf16x8 rb = load_chunk<BF32>(B, boff);
  *(bf16x8*)&At[0][lchunk] = ra;
  *(bf16x8*)&Bt[0][lchunk] = rb;
  __syncthreads();

  f32x4 acc[2][4];
  #pragma unroll
  for (int i = 0; i < 2; ++i)
    #pragma unroll
    for (int j = 0; j < 4; ++j) acc[i][j] = (f32x4){0.f, 0.f, 0.f, 0.f};

  for (int t = 0; t < 32; ++t) {
    const int cur = t & 1;
    if (t < 31) {
      ra = load_chunk<AF32>(A, aoff + (size_t)(t + 1) * 32);
      rb = load_chunk<BF32>(B, boff + (size_t)(t + 1) * 32);
    }
    bf16x8 af[2], bfr[4];
    #pragma unroll
    for (int i = 0; i < 2; ++i)
      af[i] = *(const bf16x8*)&At[cur][((lane >> 4) * 128 + wm * 32 + i * 16 + (lane & 15)) * 8];
    #pragma unroll
    for (int j = 0; j < 4; ++j)
      bfr[j] = *(const bf16x8*)&Bt[cur][((lane >> 4) * 128 + wn * 64 + j * 16 + (lane & 15)) * 8];
    __builtin_amdgcn_s_setprio(1);
    #pragma unroll
    for (int i = 0; i < 2; ++i)
      #pragma unroll
      for (int j = 0; j < 4; ++j)
        acc[i][j] = __builtin_amdgcn_mfma_f32_16x16x32_bf16(af[i], bfr[j], acc[i][j], 0, 0, 0);
    __builtin_amdgcn_s_setprio(0);
    if (t < 31) {
      *(bf16x8*)&At[cur ^ 1][lchunk] = ra;
      *(bf16x8*)&Bt[cur ^ 1][lchunk] = rb;
    }
    __syncthreads();
  }

  #pragma unroll
  for (int i = 0; i < 2; ++i) {
    #pragma unroll
    for (int j = 0; j < 4; ++j) {
      #pragma unroll
      for (int r = 0; r < 4; ++r) {
        int m = m0 + wm * 32 + i * 16 + (lane >> 4) * 4 + r;
        int n = n0 + wn * 64 + j * 16 + (lane & 15);
        float val = (acc[i][j][r] + bias[n]) * outScale;
        if (MODE == 0) {
          ((float*)C)[(size_t)m * N + n] = val;
        } else {
          int b = m >> 11, s = m & (SEQ - 1);
          int h = n >> 6,  d = n & (DK - 1);
          if (MODE == 1)
            ((ushort*)C)[((size_t)(b * NHEAD + h) * SEQ + s) * DK + d] = f2bf(val);
          else
            ((ushort*)C)[((size_t)(b * NHEAD + h) * DK + d) * SEQ + s] = f2bf(val);
        }
      }
    }
  }
}

// ---------------- MFMA attention: QBLK=64, two-pass softmax ----------------
// One block = 64 q-rows of one (b,h); 256 threads / 4 waves; wave owns keys
// [w*512, (w+1)*512). Q pre-scaled by 1/8 in its projection.
// Pass A: QK^T -> exp -> row sums only (no stores).
// Pass B: recompute QK^T per 64-key tile -> wave-private 8KB LDS tile (bf16,
// XOR chunk swizzle) -> PV MFMA + normalized fp32 attn store per tile.
// Rationale: 16-row blocks streamed 2.1 GB of K/V through L2/TA at ~16 lines
// per load instr (R4-R7 invariant, ~330us). 64-row tiles cut that 4x; the
// QK^T recompute is nearly free (MfmaUtil was 4%).
__global__ __launch_bounds__(256, 2) void attn_mfma(
    const ushort* __restrict__ Qh, const ushort* __restrict__ Kh,
    const ushort* __restrict__ Vt, float* __restrict__ attn,
    ushort* __restrict__ ctxb)
{
  __shared__ __align__(16) ushort sT[4][64 * 64];   // 4 x 8KB wave-private tiles
  __shared__ float sRed[4][64];
  __shared__ float sInv[64];

  const int tid = threadIdx.x, lane = tid & 63, wave = tid >> 6;
  const int l16 = lane & 15, lq = lane >> 4;
  // XCD swizzle: 1024 blocks = 8 XCDs x 128 -> 4 consecutive bh per XCD
  // (K+V 4 x 512KB = 2MB, L2-resident).
  const int bid  = blockIdx.x;
  const int sbid = (bid & 7) * 128 + (bid >> 3);
  const int bh = sbid >> 5;
  const int q0 = (sbid & 31) * 64;
  const ushort* Qp = Qh + ((size_t)bh * SEQ + q0) * DK;
  const ushort* Kp = Kh + (size_t)bh * SEQ * DK;
  const ushort* Vp = Vt + (size_t)bh * DK * SEQ;

  // Q B-frags, persistent: [qg][k-half]; row-space q = qg*16 + l16
  bf16x8 bq[4][2];
  #pragma unroll
  for (int qg = 0; qg < 4; ++qg) {
    bq[qg][0] = *(const bf16x8*)(Qp + (qg * 16 + l16) * DK + lq * 8);
    bq[qg][1] = *(const bf16x8*)(Qp + (qg * 16 + l16) * DK + 32 + lq * 8);
  }

  const int wkey0 = wave * 512;
  const ushort* kbase = Kp + (size_t)(wkey0 + l16) * DK + lq * 8;

  // ================= Pass A: row sums only =================
  float lsum[4] = {0.f, 0.f, 0.f, 0.f};
  {
    bf16x8 kb[2][8];
    #pragma unroll
    for (int ni = 0; ni < 4; ++ni) {
      kb[0][2 * ni]     = *(const bf16x8*)(kbase + (size_t)ni * 16 * DK);
      kb[0][2 * ni + 1] = *(const bf16x8*)(kbase + (size_t)ni * 16 * DK + 32);
    }
    for (int kt = 0; kt < 8; ++kt) {
      const int cb = kt & 1;
      if (kt < 7) {
        const ushort* kn = kbase + (size_t)(kt + 1) * 64 * DK;
        #pragma unroll
        for (int ni = 0; ni < 4; ++ni) {
          kb[cb ^ 1][2 * ni]     = *(const bf16x8*)(kn + (size_t)ni * 16 * DK);
          kb[cb ^ 1][2 * ni + 1] = *(const bf16x8*)(kn + (size_t)ni * 16 * DK + 32);
        }
      }
      #pragma unroll
      for (int ni = 0; ni < 4; ++ni) {
        f32x4 acc[4];
        __builtin_amdgcn_s_setprio(1);
        #pragma unroll
        for (int qg = 0; qg < 4; ++qg) {
          acc[qg] = (f32x4){0.f, 0.f, 0.f, 0.f};
          acc[qg] = __builtin_amdgcn_mfma_f32_16x16x32_bf16(kb[cb][2 * ni],     bq[qg][0], acc[qg], 0, 0, 0);
          acc[qg] = __builtin_amdgcn_mfma_f32_16x16x32_bf16(kb[cb][2 * ni + 1], bq[qg][1], acc[qg], 0, 0, 0);
        }
        __builtin_amdgcn_s_setprio(0);
        #pragma unroll
        for (int qg = 0; qg < 4; ++qg)
          lsum[qg] += (__expf(acc[qg][0]) + __expf(acc[qg][1]))
                    + (__expf(acc[qg][2]) + __expf(acc[qg][3]));
      }
    }
  }
  #pragma unroll
  for (int qg = 0; qg < 4; ++qg) {
    float v = lsum[qg];
    v += __shfl_xor(v, 16);
    v += __shfl_xor(v, 32);
    if (lane < 16) sRed[wave][qg * 16 + lane] = v;
  }
  __syncthreads();
  if (tid < 64)
    sInv[tid] = 1.0f / (sRed[0][tid] + sRed[1][tid] + sRed[2][tid] + sRed[3][tid]);
  __syncthreads();

  // ================= Pass B: emit attn + PV per 64-key tile =================
  ushort* tile = sT[wave];
  const ushort* vbase = Vp + (size_t)l16 * SEQ + wkey0 + lq * 8;
  f32x4 cacc[4][4];
  #pragma unroll
  for (int qg = 0; qg < 4; ++qg)
    #pragma unroll
    for (int ni = 0; ni < 4; ++ni) cacc[qg][ni] = (f32x4){0.f, 0.f, 0.f, 0.f};

  bf16x8 kb[2][8];
  #pragma unroll
  for (int ni = 0; ni < 4; ++ni) {
    kb[0][2 * ni]     = *(const bf16x8*)(kbase + (size_t)ni * 16 * DK);
    kb[0][2 * ni + 1] = *(const bf16x8*)(kbase + (size_t)ni * 16 * DK + 32);
  }

  for (int kt = 0; kt < 8; ++kt) {
    const int cb = kt & 1;
    // V for this tile (consumed after QK^T epilogue -> in-iteration prefetch)
    bf16x8 vb[2][4];
    #pragma unroll
    for (int h = 0; h < 2; ++h)
      #pragma unroll
      for (int ni = 0; ni < 4; ++ni)
        vb[h][ni] = *(const bf16x8*)(vbase + (size_t)ni * 16 * SEQ + kt * 64 + h * 32);
    // K for next tile
    if (kt < 7) {
      const ushort* kn = kbase + (size_t)(kt + 1) * 64 * DK;
      #pragma unroll
      for (int ni = 0; ni < 4; ++ni) {
        kb[cb ^ 1][2 * ni]     = *(const bf16x8*)(kn + (size_t)ni * 16 * DK);
        kb[cb ^ 1][2 * ni + 1] = *(const bf16x8*)(kn + (size_t)ni * 16 * DK + 32);
      }
    }
    // ---- QK^T (swapped: key-major) + exp -> tile (bf16, chunk^row swizzle)
    #pragma unroll
    for (int ni = 0; ni < 4; ++ni) {
      f32x4 acc[4];
      __builtin_amdgcn_s_setprio(1);
      #pragma unroll
      for (int qg = 0; qg < 4; ++qg) {
        acc[qg] = (f32x4){0.f, 0.f, 0.f, 0.f};
        acc[qg] = __builtin_amdgcn_mfma_f32_16x16x32_bf16(kb[cb][2 * ni],     bq[qg][0], acc[qg], 0, 0, 0);
        acc[qg] = __builtin_amdgcn_mfma_f32_16x16x32_bf16(kb[cb][2 * ni + 1], bq[qg][1], acc[qg], 0, 0, 0);
      }
      __builtin_amdgcn_s_setprio(0);
      #pragma unroll
      for (int qg = 0; qg < 4; ++qg) {
        float p0 = __expf(acc[qg][0]);
        float p1 = __expf(acc[qg][1]);
        float p2 = __expf(acc[qg][2]);
        float p3 = __expf(acc[qg][3]);
        ushort4 pk;
        pk.x = f2bf(p0); pk.y = f2bf(p1); pk.z = f2bf(p2); pk.w = f2bf(p3);
        const int prow = qg * 16 + l16;
        const int col = ni * 16 + lq * 4;        // 4 consecutive local keys
        *(ushort4*)&tile[prow * 64 + (((col >> 3) ^ (prow & 7)) << 3) + (col & 7)] = pk;
      }
    }
    // ---- PV from tile (wave-private; same-wave lgkm ordering)
    #pragma unroll
    for (int qg = 0; qg < 4; ++qg) {
      const int prow = qg * 16 + l16;
      const int rsw = prow & 7;
      bf16x8 pa0 = *(const bf16x8*)&tile[prow * 64 + ((lq) ^ rsw) * 8];       // k 0..31
      bf16x8 pa1 = *(const bf16x8*)&tile[prow * 64 + ((4 + lq) ^ rsw) * 8];   // k 32..63
      __builtin_amdgcn_s_setprio(1);
      #pragma unroll
      for (int ni = 0; ni < 4; ++ni)
        cacc[qg][ni] = __builtin_amdgcn_mfma_f32_16x16x32_bf16(pa0, vb[0][ni], cacc[qg][ni], 0, 0, 0);
      #pragma unroll
      for (int ni = 0; ni < 4; ++ni)
        cacc[qg][ni] = __builtin_amdgcn_mfma_f32_16x16x32_bf16(pa1, vb[1][ni], cacc[qg][ni], 0, 0, 0);
      __builtin_amdgcn_s_setprio(0);
    }
    // ---- normalized attn store for this tile (issued after all loads)
    {
      const int r8 = lane >> 3, c8 = lane & 7;
      #pragma unroll
      for (int rg = 0; rg < 8; ++rg) {
        const int prow = rg * 8 + r8;
        const float iv = sInv[prow];
        bf16x8 pv = *(const bf16x8*)&tile[prow * 64 + ((c8 ^ (prow & 7)) << 3)];
        float4 o0, o1;
        o0.x = bf2f((ushort)pv[0]) * iv; o0.y = bf2f((ushort)pv[1]) * iv;
        o0.z = bf2f((ushort)pv[2]) * iv; o0.w = bf2f((ushort)pv[3]) * iv;
        o1.x = bf2f((ushort)pv[4]) * iv; o1.y = bf2f((ushort)pv[5]) * iv;
        o1.z = bf2f((ushort)pv[6]) * iv; o1.w = bf2f((ushort)pv[7]) * iv;
        float* ap = attn + ((size_t)(bh * SEQ + q0 + prow)) * SEQ + wkey0 + kt * 64 + c8 * 8;
        *(float4*)ap = o0;
        *(float4*)(ap + 4) = o1;
      }
    }
  }

  // ================= ctx: cross-wave reduce in two 32-row halves =================
  __syncthreads();
  const int bb = bh >> 4, hh = bh & 15;
  #pragma unroll
  for (int half = 0; half < 2; ++half) {
    float* ft = (float*)sT[wave];
    #pragma unroll
    for (int hg = 0; hg < 2; ++hg) {
      const int qg = half * 2 + hg;
      #pragma unroll
      for (int ni = 0; ni < 4; ++ni)
        #pragma unroll
        for (int r = 0; r < 4; ++r)
          ft[(hg * 16 + lq * 4 + r) * 64 + ni * 16 + l16] = cacc[qg][ni][r];
    }
    __syncthreads();
    {
      const int row = tid >> 3;           // 0..31
      const int c = (tid & 7) * 8;        // 0..56
      const float iv = sInv[half * 32 + row];
      float s0 = 0.f, s1 = 0.f, s2 = 0.f, s3 = 0.f, s4 = 0.f, s5 = 0.f, s6 = 0.f, s7 = 0.f;
      #pragma unroll
      for (int w = 0; w < 4; ++w) {
        const float* fw = (const float*)sT[w] + row * 64 + c;
        s0 += fw[0]; s1 += fw[1]; s2 += fw[2]; s3 += fw[3];
        s4 += fw[4]; s5 += fw[5]; s6 += fw[6]; s7 += fw[7];
      }
      bf16x8 ob;
      ob[0] = (short)f2bf(s0 * iv); ob[1] = (short)f2bf(s1 * iv);
      ob[2] = (short)f2bf(s2 * iv); ob[3] = (short)f2bf(s3 * iv);
      ob[4] = (short)f2bf(s4 * iv); ob[5] = (short)f2bf(s5 * iv);
      ob[6] = (short)f2bf(s6 * iv); ob[7] = (short)f2bf(s7 * iv);
      *(bf16x8*)(ctxb + ((size_t)(bb * SEQ + q0 + half * 32 + row)) * D_MODEL + hh * DK + c) = ob;
    }
    __syncthreads();
  }
}

extern "C" void kernel_launch(void* const* d_in, const int* in_sizes, int n_in,
                              void* d_out, int out_size, void* d_ws, size_t ws_size,
                              hipStream_t stream)
{
  const float* q  = (const float*)d_in[0];
  const float* k  = (const float*)d_in[1];
  const float* v  = (const float*)d_in[2];
  const float* Wq = (const float*)d_in[3];
  const float* bq = (const float*)d_in[4];
  const float* Wk = (const float*)d_in[5];
  const float* bk = (const float*)d_in[6];
  const float* Wv = (const float*)d_in[7];
  const float* bv = (const float*)d_in[8];
  const float* Wo = (const float*)d_in[9];
  const float* bo = (const float*)d_in[10];

  float* out  = (float*)d_out;
  float* attn = out + (size_t)BATCH * SEQ * D_MODEL;

  const size_t XEL = (size_t)BATCH * SEQ * D_MODEL;  // 4 Mi elems
  ushort* Qhb  = (ushort*)d_ws;
  ushort* Khb  = Qhb + XEL;
  ushort* Vtb  = Khb + XEL;
  ushort* ctxb = Vtb + XEL;   // 32 MiB total

  const int M = BATCH * SEQ;
  dim3 gg(D_MODEL / 128, M / 128);   // (8, 32) = 256 blocks
  // Q projection carries the 1/8 attention scale (exact: exponent shift).
  gemm_bf16<1, true, true><<<gg, 512, 0, stream>>>(q, Wq, bq, Qhb, M, D_MODEL, D_MODEL, 0.125f);
  gemm_bf16<1, true, true><<<gg, 512, 0, stream>>>(k, Wk, bk, Khb, M, D_MODEL, D_MODEL, 1.0f);
  gemm_bf16<2, true, true><<<gg, 512, 0, stream>>>(v, Wv, bv, Vtb, M, D_MODEL, D_MODEL, 1.0f);

  attn_mfma<<<dim3(BATCH * NHEAD * (SEQ / 64)), 256, 0, stream>>>(Qhb, Khb, Vtb, attn, ctxb);

  gemm_bf16<0, false, true><<<gg, 512, 0, stream>>>(ctxb, Wo, bo, out, M, D_MODEL, D_MODEL, 1.0f);
}

// Round 9
// 441.136 us; speedup vs baseline: 1.1568x; 1.1568x over previous
//
#include <hip/hip_runtime.h>
#include <hip/hip_bf16.h>

#define D_MODEL 1024
#define NHEAD   16
#define DK      64
#define SEQ     2048
#define BATCH   2

typedef __attribute__((ext_vector_type(8))) short bf16x8;   // 8 bf16 = 4 VGPR
typedef __attribute__((ext_vector_type(4))) float f32x4;

static __device__ __forceinline__ ushort f2bf(float f) {
  union { float f; unsigned u; } x; x.f = f;
  unsigned r = x.u + 0x7FFF + ((x.u >> 16) & 1);   // round-to-nearest-even
  return (ushort)(r >> 16);
}
static __device__ __forceinline__ float bf2f(ushort b) {
  union { unsigned u; float f; } x; x.u = ((unsigned)b) << 16;
  return x.f;
}

// Load one 8-element bf16 chunk from either an fp32 or a bf16 source.
template<bool F32>
static __device__ __forceinline__ bf16x8 load_chunk(const void* base, size_t eoff) {
  if constexpr (F32) {
    const float* p = (const float*)base + eoff;
    float4 a = *(const float4*)p;
    float4 b = *(const float4*)(p + 4);
    bf16x8 o;
    o[0] = (short)f2bf(a.x); o[1] = (short)f2bf(a.y);
    o[2] = (short)f2bf(a.z); o[3] = (short)f2bf(a.w);
    o[4] = (short)f2bf(b.x); o[5] = (short)f2bf(b.y);
    o[6] = (short)f2bf(b.z); o[7] = (short)f2bf(b.w);
    return o;
  } else {
    return *(const bf16x8*)((const ushort*)base + eoff);
  }
}

// ---------------- bf16 MFMA GEMM: C = A @ B^T + bias ---------------- (as R7)
template<int MODE, bool AF32, bool BF32>
__global__ __launch_bounds__(512) void gemm_bf16(
    const void* __restrict__ A, const void* __restrict__ B,
    const float* __restrict__ bias, void* __restrict__ C,
    int M, int N, int K, float outScale)
{
  __shared__ __align__(16) ushort At[2][128 * 32];
  __shared__ __align__(16) ushort Bt[2][128 * 32];
  const int tid = threadIdx.x;
  const int lane = tid & 63, wave = tid >> 6;
  const int wm = wave >> 1, wn = wave & 1;
  const int m0 = blockIdx.y * 128, n0 = blockIdx.x * 128;
  const int row = tid >> 2, kc = tid & 3;
  const size_t aoff = (size_t)(m0 + row) * K + kc * 8;
  const size_t boff = (size_t)(n0 + row) * K + kc * 8;
  const int lchunk = (kc * 128 + row) * 8;

  bf16x8 ra = load_chunk<AF32>(A, aoff);
  bf16x8 rb = load_chunk<BF32>(B, boff);
  *(bf16x8*)&At[0][lchunk] = ra;
  *(bf16x8*)&Bt[0][lchunk] = rb;
  __syncthreads();

  f32x4 acc[2][4];
  #pragma unroll
  for (int i = 0; i < 2; ++i)
    #pragma unroll
    for (int j = 0; j < 4; ++j) acc[i][j] = (f32x4){0.f, 0.f, 0.f, 0.f};

  for (int t = 0; t < 32; ++t) {
    const int cur = t & 1;
    if (t < 31) {
      ra = load_chunk<AF32>(A, aoff + (size_t)(t + 1) * 32);
      rb = load_chunk<BF32>(B, boff + (size_t)(t + 1) * 32);
    }
    bf16x8 af[2], bfr[4];
    #pragma unroll
    for (int i = 0; i < 2; ++i)
      af[i] = *(const bf16x8*)&At[cur][((lane >> 4) * 128 + wm * 32 + i * 16 + (lane & 15)) * 8];
    #pragma unroll
    for (int j = 0; j < 4; ++j)
      bfr[j] = *(const bf16x8*)&Bt[cur][((lane >> 4) * 128 + wn * 64 + j * 16 + (lane & 15)) * 8];
    __builtin_amdgcn_s_setprio(1);
    #pragma unroll
    for (int i = 0; i < 2; ++i)
      #pragma unroll
      for (int j = 0; j < 4; ++j)
        acc[i][j] = __builtin_amdgcn_mfma_f32_16x16x32_bf16(af[i], bfr[j], acc[i][j], 0, 0, 0);
    __builtin_amdgcn_s_setprio(0);
    if (t < 31) {
      *(bf16x8*)&At[cur ^ 1][lchunk] = ra;
      *(bf16x8*)&Bt[cur ^ 1][lchunk] = rb;
    }
    __syncthreads();
  }

  #pragma unroll
  for (int i = 0; i < 2; ++i) {
    #pragma unroll
    for (int j = 0; j < 4; ++j) {
      #pragma unroll
      for (int r = 0; r < 4; ++r) {
        int m = m0 + wm * 32 + i * 16 + (lane >> 4) * 4 + r;
        int n = n0 + wn * 64 + j * 16 + (lane & 15);
        float val = (acc[i][j][r] + bias[n]) * outScale;
        if (MODE == 0) {
          ((float*)C)[(size_t)m * N + n] = val;
        } else {
          int b = m >> 11, s = m & (SEQ - 1);
          int h = n >> 6,  d = n & (DK - 1);
          if (MODE == 1)
            ((ushort*)C)[((size_t)(b * NHEAD + h) * SEQ + s) * DK + d] = f2bf(val);
          else
            ((ushort*)C)[((size_t)(b * NHEAD + h) * DK + d) * SEQ + s] = f2bf(val);
        }
      }
    }
  }
}

// ---------------- MFMA attention (R7 structure; FULL-LINE attn stores) ----------------
// One block = 16 q-rows of one (b,h); 512 threads / 8 waves; wave w owns keys
// [w*256, w*256+256). Q pre-scaled by 1/8 in its projection.
// R9 change vs R7: attn store loop emits 1024B-contiguous wave instructions
// (lane i -> float4 at row*SEQ + chunk*256 + lane*4). R8 evidence: the old
// 16B-per-lane-at-32B-stride pattern caused partial-sector RMW (WRITE 1.9x
// logical + 276MB extra FETCH) -- that tax, not compute, was the ~330us floor.
__global__ __launch_bounds__(512) void attn_mfma(
    const ushort* __restrict__ Qh, const ushort* __restrict__ Kh,
    const ushort* __restrict__ Vt, float* __restrict__ attn,
    ushort* __restrict__ ctxb)
{
  __shared__ __align__(16) ushort sP[16 * SEQ];   // 64 KB bf16 p=exp(s)
  __shared__ float sRed[8][16];
  __shared__ float sSum[16];

  const int tid = threadIdx.x;
  const int lane = tid & 63, wave = tid >> 6;     // 8 waves
  const int l16 = lane & 15, lq = lane >> 4;
  // XCD swizzle: 4096 blocks = 8 XCDs x 512; 4 consecutive bh per XCD.
  const int bid  = blockIdx.x;
  const int sbid = (bid & 7) * 512 + (bid >> 3);
  const int bh = sbid >> 7;
  const int q0 = (sbid & 127) * 16;
  const ushort* Qp = Qh + ((size_t)bh * SEQ + q0) * DK;
  const ushort* Kp = Kh + (size_t)bh * SEQ * DK;
  const ushort* Vp = Vt + (size_t)bh * DK * SEQ;

  // Q fragments (B-operand of swapped MFMA): row-space = q = l16
  bf16x8 bq0 = *(const bf16x8*)(Qp + l16 * DK + lq * 8);
  bf16x8 bq1 = *(const bf16x8*)(Qp + l16 * DK + 32 + lq * 8);

  // ---- Phase 1: swapped QK^T: acc = mfma(K_frag, Q_frag) ----
  bf16x8 kb[2][8];
  const ushort* kbase = Kp + (size_t)(wave * 256 + l16) * DK + lq * 8;
  #pragma unroll
  for (int ni = 0; ni < 4; ++ni) {
    kb[0][2 * ni]     = *(const bf16x8*)(kbase + (size_t)ni * 16 * DK);
    kb[0][2 * ni + 1] = *(const bf16x8*)(kbase + (size_t)ni * 16 * DK + 32);
  }
  float lsum = 0.f;                               // row sum for q = l16
  const int swz = l16 & 7;
  #pragma unroll
  for (int it = 0; it < 4; ++it) {
    const int cb = it & 1;
    if (it < 3) {
      const ushort* kn = kbase + (size_t)(it + 1) * 64 * DK;
      #pragma unroll
      for (int ni = 0; ni < 4; ++ni) {
        kb[cb ^ 1][2 * ni]     = *(const bf16x8*)(kn + (size_t)ni * 16 * DK);
        kb[cb ^ 1][2 * ni + 1] = *(const bf16x8*)(kn + (size_t)ni * 16 * DK + 32);
      }
    }
    f32x4 acc[4];
    __builtin_amdgcn_s_setprio(1);
    #pragma unroll
    for (int ni = 0; ni < 4; ++ni) {
      acc[ni] = (f32x4){0.f, 0.f, 0.f, 0.f};
      acc[ni] = __builtin_amdgcn_mfma_f32_16x16x32_bf16(kb[cb][2 * ni],     bq0, acc[ni], 0, 0, 0);
      acc[ni] = __builtin_amdgcn_mfma_f32_16x16x32_bf16(kb[cb][2 * ni + 1], bq1, acc[ni], 0, 0, 0);
    }
    __builtin_amdgcn_s_setprio(0);
    const int key0 = wave * 256 + it * 64;
    #pragma unroll
    for (int ni = 0; ni < 4; ++ni) {
      float p0 = __expf(acc[ni][0]);
      float p1 = __expf(acc[ni][1]);
      float p2 = __expf(acc[ni][2]);
      float p3 = __expf(acc[ni][3]);
      lsum += (p0 + p1) + (p2 + p3);
      ushort4 pk;
      pk.x = f2bf(p0); pk.y = f2bf(p1); pk.z = f2bf(p2); pk.w = f2bf(p3);
      int col = key0 + ni * 16 + lq * 4;           // 4 consecutive keys
      int chunk = col >> 3;
      *(ushort4*)&sP[l16 * SEQ + ((chunk ^ swz) << 3) + (col & 7)] = pk;
    }
  }

  // ---- row-sum reduce ----
  lsum += __shfl_xor(lsum, 16);
  lsum += __shfl_xor(lsum, 32);
  if (lane < 16) sRed[wave][lane] = lsum;
  __syncthreads();
  if (tid < 16) {
    float s = 0.f;
    #pragma unroll
    for (int w = 0; w < 8; ++w) s += sRed[w][tid];
    sSum[tid] = s;
  }
  __syncthreads();

  // ---- Phase 2: PV only (pure loads + MFMA, no stores). ----
  f32x4 cacc[4];
  #pragma unroll
  for (int ni = 0; ni < 4; ++ni) cacc[ni] = (f32x4){0.f, 0.f, 0.f, 0.f};

  const ushort* sProw = sP + l16 * SEQ;            // P row q=l16 (A-frag)
  const ushort* vbase = Vp + (size_t)l16 * SEQ + wave * 256 + lq * 8;
  bf16x8 vb[4][4];
  #pragma unroll
  for (int s = 0; s < 3; ++s)
    #pragma unroll
    for (int ni = 0; ni < 4; ++ni)
      vb[s][ni] = *(const bf16x8*)(vbase + (size_t)ni * 16 * SEQ + s * 32);
  bf16x8 pa[2];
  pa[0] = *(const bf16x8*)&sProw[((wave * 32 + lq) ^ swz) * 8];

  #pragma unroll
  for (int ks = 0; ks < 8; ++ks) {
    if (ks < 5) {
      #pragma unroll
      for (int ni = 0; ni < 4; ++ni)
        vb[(ks + 3) & 3][ni] = *(const bf16x8*)(vbase + (size_t)ni * 16 * SEQ + (ks + 3) * 32);
    }
    if (ks < 7)
      pa[(ks + 1) & 1] = *(const bf16x8*)&sProw[((wave * 32 + (ks + 1) * 4 + lq) ^ swz) * 8];
    __builtin_amdgcn_s_setprio(1);
    #pragma unroll
    for (int ni = 0; ni < 4; ++ni)
      cacc[ni] = __builtin_amdgcn_mfma_f32_16x16x32_bf16(pa[ks & 1], vb[ks & 3][ni], cacc[ni], 0, 0, 0);
    __builtin_amdgcn_s_setprio(0);
  }

  // ---- Phase 3: attn store loop -- FULL-LINE pattern ----
  // Wave handles rows {wave*2, wave*2+1}; per row, 8 store instructions,
  // each: 64 lanes x float4 = 1024 contiguous bytes (no partial sectors).
  #pragma unroll
  for (int rr = 0; rr < 2; ++rr) {
    const int prow = wave * 2 + rr;
    const float invw = 1.0f / sSum[prow];
    const int rswz = prow & 7;
    const ushort* rowp = sP + prow * SEQ;
    float* attnRow = attn + ((size_t)(bh * SEQ + q0 + prow)) * SEQ;
    #pragma unroll
    for (int i = 0; i < 8; ++i) {
      const int col = i * 256 + lane * 4;            // 4 consecutive fp32 keys
      const int chunk = (col >> 3) ^ rswz;
      ushort4 pv = *(const ushort4*)&rowp[(chunk << 3) + (col & 7)];
      float4 o;
      o.x = bf2f(pv.x) * invw;
      o.y = bf2f(pv.y) * invw;
      o.z = bf2f(pv.z) * invw;
      o.w = bf2f(pv.w) * invw;
      *(float4*)&attnRow[col] = o;
    }
  }

  // ---- Phase 4: cross-wave reduce (reuse sP as f32 scratch) + ctx bf16 ----
  __syncthreads();   // all LDS reads of sP done -> safe to overwrite
  float* sC = (float*)sP;   // [8][16][64] = 32 KB
  #pragma unroll
  for (int ni = 0; ni < 4; ++ni)
    #pragma unroll
    for (int r = 0; r < 4; ++r)
      sC[wave * 1024 + (lq * 4 + r) * 64 + ni * 16 + l16] = cacc[ni][r];
  __syncthreads();
  if (tid < 256) {
    const int qq = tid >> 4, dv = (tid & 15) * 4;
    float sx = 0.f, sy = 0.f, sz = 0.f, sw = 0.f;
    #pragma unroll
    for (int w = 0; w < 8; ++w) {
      float4 t = *(float4*)&sC[w * 1024 + qq * 64 + dv];
      sx += t.x; sy += t.y; sz += t.z; sw += t.w;
    }
    float iv = 1.0f / sSum[qq];
    ushort4 ob;
    ob.x = f2bf(sx * iv);
    ob.y = f2bf(sy * iv);
    ob.z = f2bf(sz * iv);
    ob.w = f2bf(sw * iv);
    const int bb = bh >> 4, hh = bh & 15;
    *(ushort4*)(ctxb + ((size_t)(bb * SEQ + q0 + qq)) * D_MODEL + hh * DK + dv) = ob;
  }
}

extern "C" void kernel_launch(void* const* d_in, const int* in_sizes, int n_in,
                              void* d_out, int out_size, void* d_ws, size_t ws_size,
                              hipStream_t stream)
{
  const float* q  = (const float*)d_in[0];
  const float* k  = (const float*)d_in[1];
  const float* v  = (const float*)d_in[2];
  const float* Wq = (const float*)d_in[3];
  const float* bq = (const float*)d_in[4];
  const float* Wk = (const float*)d_in[5];
  const float* bk = (const float*)d_in[6];
  const float* Wv = (const float*)d_in[7];
  const float* bv = (const float*)d_in[8];
  const float* Wo = (const float*)d_in[9];
  const float* bo = (const float*)d_in[10];

  float* out  = (float*)d_out;
  float* attn = out + (size_t)BATCH * SEQ * D_MODEL;

  const size_t XEL = (size_t)BATCH * SEQ * D_MODEL;  // 4 Mi elems
  ushort* Qhb  = (ushort*)d_ws;
  ushort* Khb  = Qhb + XEL;
  ushort* Vtb  = Khb + XEL;
  ushort* ctxb = Vtb + XEL;   // 32 MiB total

  const int M = BATCH * SEQ;
  dim3 gg(D_MODEL / 128, M / 128);   // (8, 32) = 256 blocks
  // Q projection carries the 1/8 attention scale (exact: exponent shift).
  gemm_bf16<1, true, true><<<gg, 512, 0, stream>>>(q, Wq, bq, Qhb, M, D_MODEL, D_MODEL, 0.125f);
  gemm_bf16<1, true, true><<<gg, 512, 0, stream>>>(k, Wk, bk, Khb, M, D_MODEL, D_MODEL, 1.0f);
  gemm_bf16<2, true, true><<<gg, 512, 0, stream>>>(v, Wv, bv, Vtb, M, D_MODEL, D_MODEL, 1.0f);

  attn_mfma<<<dim3(BATCH * NHEAD * SEQ / 16), 512, 0, stream>>>(Qhb, Khb, Vtb, attn, ctxb);

  gemm_bf16<0, false, true><<<gg, 512, 0, stream>>>(ctxb, Wo, bo, out, M, D_MODEL, D_MODEL, 1.0f);
}

// Round 10
// 394.454 us; speedup vs baseline: 1.2937x; 1.1183x over previous
//
#include <hip/hip_runtime.h>
#include <hip/hip_bf16.h>

#define D_MODEL 1024
#define NHEAD   16
#define DK      64
#define SEQ     2048
#define BATCH   2

typedef __attribute__((ext_vector_type(8))) short bf16x8;   // 8 bf16 = 4 VGPR
typedef __attribute__((ext_vector_type(4))) float f32x4;

static __device__ __forceinline__ ushort f2bf(float f) {
  union { float f; unsigned u; } x; x.f = f;
  unsigned r = x.u + 0x7FFF + ((x.u >> 16) & 1);   // round-to-nearest-even
  return (ushort)(r >> 16);
}
static __device__ __forceinline__ float bf2f(ushort b) {
  union { unsigned u; float f; } x; x.u = ((unsigned)b) << 16;
  return x.f;
}

// Load one 8-element bf16 chunk from either an fp32 or a bf16 source.
template<bool F32>
static __device__ __forceinline__ bf16x8 load_chunk(const void* base, size_t eoff) {
  if constexpr (F32) {
    const float* p = (const float*)base + eoff;
    float4 a = *(const float4*)p;
    float4 b = *(const float4*)(p + 4);
    bf16x8 o;
    o[0] = (short)f2bf(a.x); o[1] = (short)f2bf(a.y);
    o[2] = (short)f2bf(a.z); o[3] = (short)f2bf(a.w);
    o[4] = (short)f2bf(b.x); o[5] = (short)f2bf(b.y);
    o[6] = (short)f2bf(b.z); o[7] = (short)f2bf(b.w);
    return o;
  } else {
    return *(const bf16x8*)((const ushort*)base + eoff);
  }
}

// ---------------- bf16 MFMA GEMM: C = A @ B^T + bias ---------------- (as R7)
template<int MODE, bool AF32, bool BF32>
__global__ __launch_bounds__(512) void gemm_bf16(
    const void* __restrict__ A, const void* __restrict__ B,
    const float* __restrict__ bias, void* __restrict__ C,
    int M, int N, int K, float outScale)
{
  __shared__ __align__(16) ushort At[2][128 * 32];
  __shared__ __align__(16) ushort Bt[2][128 * 32];
  const int tid = threadIdx.x;
  const int lane = tid & 63, wave = tid >> 6;
  const int wm = wave >> 1, wn = wave & 1;
  const int m0 = blockIdx.y * 128, n0 = blockIdx.x * 128;
  const int row = tid >> 2, kc = tid & 3;
  const size_t aoff = (size_t)(m0 + row) * K + kc * 8;
  const size_t boff = (size_t)(n0 + row) * K + kc * 8;
  const int lchunk = (kc * 128 + row) * 8;

  bf16x8 ra = load_chunk<AF32>(A, aoff);
  bf16x8 rb = load_chunk<BF32>(B, boff);
  *(bf16x8*)&At[0][lchunk] = ra;
  *(bf16x8*)&Bt[0][lchunk] = rb;
  __syncthreads();

  f32x4 acc[2][4];
  #pragma unroll
  for (int i = 0; i < 2; ++i)
    #pragma unroll
    for (int j = 0; j < 4; ++j) acc[i][j] = (f32x4){0.f, 0.f, 0.f, 0.f};

  for (int t = 0; t < 32; ++t) {
    const int cur = t & 1;
    if (t < 31) {
      ra = load_chunk<AF32>(A, aoff + (size_t)(t + 1) * 32);
      rb = load_chunk<BF32>(B, boff + (size_t)(t + 1) * 32);
    }
    bf16x8 af[2], bfr[4];
    #pragma unroll
    for (int i = 0; i < 2; ++i)
      af[i] = *(const bf16x8*)&At[cur][((lane >> 4) * 128 + wm * 32 + i * 16 + (lane & 15)) * 8];
    #pragma unroll
    for (int j = 0; j < 4; ++j)
      bfr[j] = *(const bf16x8*)&Bt[cur][((lane >> 4) * 128 + wn * 64 + j * 16 + (lane & 15)) * 8];
    __builtin_amdgcn_s_setprio(1);
    #pragma unroll
    for (int i = 0; i < 2; ++i)
      #pragma unroll
      for (int j = 0; j < 4; ++j)
        acc[i][j] = __builtin_amdgcn_mfma_f32_16x16x32_bf16(af[i], bfr[j], acc[i][j], 0, 0, 0);
    __builtin_amdgcn_s_setprio(0);
    if (t < 31) {
      *(bf16x8*)&At[cur ^ 1][lchunk] = ra;
      *(bf16x8*)&Bt[cur ^ 1][lchunk] = rb;
    }
    __syncthreads();
  }

  #pragma unroll
  for (int i = 0; i < 2; ++i) {
    #pragma unroll
    for (int j = 0; j < 4; ++j) {
      #pragma unroll
      for (int r = 0; r < 4; ++r) {
        int m = m0 + wm * 32 + i * 16 + (lane >> 4) * 4 + r;
        int n = n0 + wn * 64 + j * 16 + (lane & 15);
        float val = (acc[i][j][r] + bias[n]) * outScale;
        if (MODE == 0) {
          ((float*)C)[(size_t)m * N + n] = val;
        } else {
          int b = m >> 11, s = m & (SEQ - 1);
          int h = n >> 6,  d = n & (DK - 1);
          if (MODE == 1)
            ((ushort*)C)[((size_t)(b * NHEAD + h) * SEQ + s) * DK + d] = f2bf(val);
          else
            ((ushort*)C)[((size_t)(b * NHEAD + h) * DK + d) * SEQ + s] = f2bf(val);
        }
      }
    }
  }
}

// ---------------- MFMA attention: QBLK=64, two-pass softmax ----------------
// R10 = R8 structure with the attn store block rewritten:
//   - full-line pattern: per instruction 4 rows x 16 lanes x 16B -> each row
//     segment 256B contiguous (no partial sectors, no RMW; R8 measured
//     WRITE 1.9x logical + 276MB parasitic FETCH from the old 16B@32B-stride
//     pattern, R9 proved the clean pattern removes it)
//   - __builtin_nontemporal_store: attn is write-once/never-read -> bypass
//     L2 allocation, keep K/V resident, save L2 evict BW.
// 64-row tile quarters K/V L2 traffic vs the 16-row structure (R4-R9 floor).
__global__ __launch_bounds__(256, 2) void attn_mfma(
    const ushort* __restrict__ Qh, const ushort* __restrict__ Kh,
    const ushort* __restrict__ Vt, float* __restrict__ attn,
    ushort* __restrict__ ctxb)
{
  __shared__ __align__(16) ushort sT[4][64 * 64];   // 4 x 8KB wave-private tiles
  __shared__ float sRed[4][64];
  __shared__ float sInv[64];

  const int tid = threadIdx.x, lane = tid & 63, wave = tid >> 6;
  const int l16 = lane & 15, lq = lane >> 4;
  // XCD swizzle: 1024 blocks = 8 XCDs x 128 -> 4 consecutive bh per XCD
  // (K+V 4 x 512KB = 2MB, L2-resident).
  const int bid  = blockIdx.x;
  const int sbid = (bid & 7) * 128 + (bid >> 3);
  const int bh = sbid >> 5;
  const int q0 = (sbid & 31) * 64;
  const ushort* Qp = Qh + ((size_t)bh * SEQ + q0) * DK;
  const ushort* Kp = Kh + (size_t)bh * SEQ * DK;
  const ushort* Vp = Vt + (size_t)bh * DK * SEQ;

  // Q B-frags, persistent: [qg][k-half]; row-space q = qg*16 + l16
  bf16x8 bq[4][2];
  #pragma unroll
  for (int qg = 0; qg < 4; ++qg) {
    bq[qg][0] = *(const bf16x8*)(Qp + (qg * 16 + l16) * DK + lq * 8);
    bq[qg][1] = *(const bf16x8*)(Qp + (qg * 16 + l16) * DK + 32 + lq * 8);
  }

  const int wkey0 = wave * 512;
  const ushort* kbase = Kp + (size_t)(wkey0 + l16) * DK + lq * 8;

  // ================= Pass A: row sums only =================
  float lsum[4] = {0.f, 0.f, 0.f, 0.f};
  {
    bf16x8 kb[2][8];
    #pragma unroll
    for (int ni = 0; ni < 4; ++ni) {
      kb[0][2 * ni]     = *(const bf16x8*)(kbase + (size_t)ni * 16 * DK);
      kb[0][2 * ni + 1] = *(const bf16x8*)(kbase + (size_t)ni * 16 * DK + 32);
    }
    for (int kt = 0; kt < 8; ++kt) {
      const int cb = kt & 1;
      if (kt < 7) {
        const ushort* kn = kbase + (size_t)(kt + 1) * 64 * DK;
        #pragma unroll
        for (int ni = 0; ni < 4; ++ni) {
          kb[cb ^ 1][2 * ni]     = *(const bf16x8*)(kn + (size_t)ni * 16 * DK);
          kb[cb ^ 1][2 * ni + 1] = *(const bf16x8*)(kn + (size_t)ni * 16 * DK + 32);
        }
      }
      #pragma unroll
      for (int ni = 0; ni < 4; ++ni) {
        f32x4 acc[4];
        __builtin_amdgcn_s_setprio(1);
        #pragma unroll
        for (int qg = 0; qg < 4; ++qg) {
          acc[qg] = (f32x4){0.f, 0.f, 0.f, 0.f};
          acc[qg] = __builtin_amdgcn_mfma_f32_16x16x32_bf16(kb[cb][2 * ni],     bq[qg][0], acc[qg], 0, 0, 0);
          acc[qg] = __builtin_amdgcn_mfma_f32_16x16x32_bf16(kb[cb][2 * ni + 1], bq[qg][1], acc[qg], 0, 0, 0);
        }
        __builtin_amdgcn_s_setprio(0);
        #pragma unroll
        for (int qg = 0; qg < 4; ++qg)
          lsum[qg] += (__expf(acc[qg][0]) + __expf(acc[qg][1]))
                    + (__expf(acc[qg][2]) + __expf(acc[qg][3]));
      }
    }
  }
  #pragma unroll
  for (int qg = 0; qg < 4; ++qg) {
    float v = lsum[qg];
    v += __shfl_xor(v, 16);
    v += __shfl_xor(v, 32);
    if (lane < 16) sRed[wave][qg * 16 + lane] = v;
  }
  __syncthreads();
  if (tid < 64)
    sInv[tid] = 1.0f / (sRed[0][tid] + sRed[1][tid] + sRed[2][tid] + sRed[3][tid]);
  __syncthreads();

  // ================= Pass B: emit attn + PV per 64-key tile =================
  ushort* tile = sT[wave];
  const ushort* vbase = Vp + (size_t)l16 * SEQ + wkey0 + lq * 8;
  f32x4 cacc[4][4];
  #pragma unroll
  for (int qg = 0; qg < 4; ++qg)
    #pragma unroll
    for (int ni = 0; ni < 4; ++ni) cacc[qg][ni] = (f32x4){0.f, 0.f, 0.f, 0.f};

  bf16x8 kb[2][8];
  #pragma unroll
  for (int ni = 0; ni < 4; ++ni) {
    kb[0][2 * ni]     = *(const bf16x8*)(kbase + (size_t)ni * 16 * DK);
    kb[0][2 * ni + 1] = *(const bf16x8*)(kbase + (size_t)ni * 16 * DK + 32);
  }

  for (int kt = 0; kt < 8; ++kt) {
    const int cb = kt & 1;
    // V for this tile (consumed after QK^T epilogue -> in-iteration prefetch)
    bf16x8 vb[2][4];
    #pragma unroll
    for (int h = 0; h < 2; ++h)
      #pragma unroll
      for (int ni = 0; ni < 4; ++ni)
        vb[h][ni] = *(const bf16x8*)(vbase + (size_t)ni * 16 * SEQ + kt * 64 + h * 32);
    // K for next tile
    if (kt < 7) {
      const ushort* kn = kbase + (size_t)(kt + 1) * 64 * DK;
      #pragma unroll
      for (int ni = 0; ni < 4; ++ni) {
        kb[cb ^ 1][2 * ni]     = *(const bf16x8*)(kn + (size_t)ni * 16 * DK);
        kb[cb ^ 1][2 * ni + 1] = *(const bf16x8*)(kn + (size_t)ni * 16 * DK + 32);
      }
    }
    // ---- QK^T (swapped: key-major) + exp -> tile (bf16, chunk^row swizzle)
    #pragma unroll
    for (int ni = 0; ni < 4; ++ni) {
      f32x4 acc[4];
      __builtin_amdgcn_s_setprio(1);
      #pragma unroll
      for (int qg = 0; qg < 4; ++qg) {
        acc[qg] = (f32x4){0.f, 0.f, 0.f, 0.f};
        acc[qg] = __builtin_amdgcn_mfma_f32_16x16x32_bf16(kb[cb][2 * ni],     bq[qg][0], acc[qg], 0, 0, 0);
        acc[qg] = __builtin_amdgcn_mfma_f32_16x16x32_bf16(kb[cb][2 * ni + 1], bq[qg][1], acc[qg], 0, 0, 0);
      }
      __builtin_amdgcn_s_setprio(0);
      #pragma unroll
      for (int qg = 0; qg < 4; ++qg) {
        float p0 = __expf(acc[qg][0]);
        float p1 = __expf(acc[qg][1]);
        float p2 = __expf(acc[qg][2]);
        float p3 = __expf(acc[qg][3]);
        ushort4 pk;
        pk.x = f2bf(p0); pk.y = f2bf(p1); pk.z = f2bf(p2); pk.w = f2bf(p3);
        const int prow = qg * 16 + l16;
        const int col = ni * 16 + lq * 4;        // 4 consecutive local keys
        *(ushort4*)&tile[prow * 64 + (((col >> 3) ^ (prow & 7)) << 3) + (col & 7)] = pk;
      }
    }
    // ---- PV from tile (wave-private; same-wave lgkm ordering)
    #pragma unroll
    for (int qg = 0; qg < 4; ++qg) {
      const int prow = qg * 16 + l16;
      const int rsw = prow & 7;
      bf16x8 pa0 = *(const bf16x8*)&tile[prow * 64 + ((lq) ^ rsw) * 8];       // k 0..31
      bf16x8 pa1 = *(const bf16x8*)&tile[prow * 64 + ((4 + lq) ^ rsw) * 8];   // k 32..63
      __builtin_amdgcn_s_setprio(1);
      #pragma unroll
      for (int ni = 0; ni < 4; ++ni)
        cacc[qg][ni] = __builtin_amdgcn_mfma_f32_16x16x32_bf16(pa0, vb[0][ni], cacc[qg][ni], 0, 0, 0);
      #pragma unroll
      for (int ni = 0; ni < 4; ++ni)
        cacc[qg][ni] = __builtin_amdgcn_mfma_f32_16x16x32_bf16(pa1, vb[1][ni], cacc[qg][ni], 0, 0, 0);
      __builtin_amdgcn_s_setprio(0);
    }
    // ---- normalized attn store: FULL-LINE nontemporal pattern ----
    // Per instruction: 4 rows x 16 lanes x 16B -> 256B contiguous per row.
    {
      const int r4 = lane >> 4;            // 0..3
      const int c16 = lane & 15;           // 0..15
      const int col = c16 * 4;             // local key, 4 fp32 = 16B
      #pragma unroll
      for (int rg = 0; rg < 16; ++rg) {
        const int prow = rg * 4 + r4;
        const float iv = sInv[prow];
        const int chunk = (col >> 3) ^ (prow & 7);
        ushort4 pv = *(const ushort4*)&tile[prow * 64 + (chunk << 3) + (col & 7)];
        f32x4 o;
        o[0] = bf2f(pv.x) * iv;
        o[1] = bf2f(pv.y) * iv;
        o[2] = bf2f(pv.z) * iv;
        o[3] = bf2f(pv.w) * iv;
        float* ap = attn + ((size_t)(bh * SEQ + q0 + prow)) * SEQ + wkey0 + kt * 64 + col;
        __builtin_nontemporal_store(o, (f32x4*)ap);
      }
    }
  }

  // ================= ctx: cross-wave reduce in two 32-row halves =================
  __syncthreads();
  const int bb = bh >> 4, hh = bh & 15;
  #pragma unroll
  for (int half = 0; half < 2; ++half) {
    float* ft = (float*)sT[wave];
    #pragma unroll
    for (int hg = 0; hg < 2; ++hg) {
      const int qg = half * 2 + hg;
      #pragma unroll
      for (int ni = 0; ni < 4; ++ni)
        #pragma unroll
        for (int r = 0; r < 4; ++r)
          ft[(hg * 16 + lq * 4 + r) * 64 + ni * 16 + l16] = cacc[qg][ni][r];
    }
    __syncthreads();
    {
      const int row = tid >> 3;           // 0..31
      const int c = (tid & 7) * 8;        // 0..56
      const float iv = sInv[half * 32 + row];
      float s0 = 0.f, s1 = 0.f, s2 = 0.f, s3 = 0.f, s4 = 0.f, s5 = 0.f, s6 = 0.f, s7 = 0.f;
      #pragma unroll
      for (int w = 0; w < 4; ++w) {
        const float* fw = (const float*)sT[w] + row * 64 + c;
        s0 += fw[0]; s1 += fw[1]; s2 += fw[2]; s3 += fw[3];
        s4 += fw[4]; s5 += fw[5]; s6 += fw[6]; s7 += fw[7];
      }
      bf16x8 ob;
      ob[0] = (short)f2bf(s0 * iv); ob[1] = (short)f2bf(s1 * iv);
      ob[2] = (short)f2bf(s2 * iv); ob[3] = (short)f2bf(s3 * iv);
      ob[4] = (short)f2bf(s4 * iv); ob[5] = (short)f2bf(s5 * iv);
      ob[6] = (short)f2bf(s6 * iv); ob[7] = (short)f2bf(s7 * iv);
      *(bf16x8*)(ctxb + ((size_t)(bb * SEQ + q0 + half * 32 + row)) * D_MODEL + hh * DK + c) = ob;
    }
    __syncthreads();
  }
}

extern "C" void kernel_launch(void* const* d_in, const int* in_sizes, int n_in,
                              void* d_out, int out_size, void* d_ws, size_t ws_size,
                              hipStream_t stream)
{
  const float* q  = (const float*)d_in[0];
  const float* k  = (const float*)d_in[1];
  const float* v  = (const float*)d_in[2];
  const float* Wq = (const float*)d_in[3];
  const float* bq = (const float*)d_in[4];
  const float* Wk = (const float*)d_in[5];
  const float* bk = (const float*)d_in[6];
  const float* Wv = (const float*)d_in[7];
  const float* bv = (const float*)d_in[8];
  const float* Wo = (const float*)d_in[9];
  const float* bo = (const float*)d_in[10];

  float* out  = (float*)d_out;
  float* attn = out + (size_t)BATCH * SEQ * D_MODEL;

  const size_t XEL = (size_t)BATCH * SEQ * D_MODEL;  // 4 Mi elems
  ushort* Qhb  = (ushort*)d_ws;
  ushort* Khb  = Qhb + XEL;
  ushort* Vtb  = Khb + XEL;
  ushort* ctxb = Vtb + XEL;   // 32 MiB total

  const int M = BATCH * SEQ;
  dim3 gg(D_MODEL / 128, M / 128);   // (8, 32) = 256 blocks
  // Q projection carries the 1/8 attention scale (exact: exponent shift).
  gemm_bf16<1, true, true><<<gg, 512, 0, stream>>>(q, Wq, bq, Qhb, M, D_MODEL, D_MODEL, 0.125f);
  gemm_bf16<1, true, true><<<gg, 512, 0, stream>>>(k, Wk, bk, Khb, M, D_MODEL, D_MODEL, 1.0f);
  gemm_bf16<2, true, true><<<gg, 512, 0, stream>>>(v, Wv, bv, Vtb, M, D_MODEL, D_MODEL, 1.0f);

  attn_mfma<<<dim3(BATCH * NHEAD * (SEQ / 64)), 256, 0, stream>>>(Qhb, Khb, Vtb, attn, ctxb);

  gemm_bf16<0, false, true><<<gg, 512, 0, stream>>>(ctxb, Wo, bo, out, M, D_MODEL, D_MODEL, 1.0f);
}

// Round 11
// 319.636 us; speedup vs baseline: 1.5965x; 1.2341x over previous
//
#include <hip/hip_runtime.h>
#include <hip/hip_bf16.h>

#define D_MODEL 1024
#define NHEAD   16
#define DK      64
#define SEQ     2048
#define BATCH   2

typedef __attribute__((ext_vector_type(8))) short bf16x8;   // 8 bf16 = 4 VGPR
typedef __attribute__((ext_vector_type(4))) float f32x4;

static __device__ __forceinline__ ushort f2bf(float f) {
  union { float f; unsigned u; } x; x.f = f;
  unsigned r = x.u + 0x7FFF + ((x.u >> 16) & 1);   // round-to-nearest-even
  return (ushort)(r >> 16);
}
static __device__ __forceinline__ float bf2f(ushort b) {
  union { unsigned u; float f; } x; x.u = ((unsigned)b) << 16;
  return x.f;
}

// Load one 8-element bf16 chunk from either an fp32 or a bf16 source.
template<bool F32>
static __device__ __forceinline__ bf16x8 load_chunk(const void* base, size_t eoff) {
  if constexpr (F32) {
    const float* p = (const float*)base + eoff;
    float4 a = *(const float4*)p;
    float4 b = *(const float4*)(p + 4);
    bf16x8 o;
    o[0] = (short)f2bf(a.x); o[1] = (short)f2bf(a.y);
    o[2] = (short)f2bf(a.z); o[3] = (short)f2bf(a.w);
    o[4] = (short)f2bf(b.x); o[5] = (short)f2bf(b.y);
    o[6] = (short)f2bf(b.z); o[7] = (short)f2bf(b.w);
    return o;
  } else {
    return *(const bf16x8*)((const ushort*)base + eoff);
  }
}

// ---------------- Fused QKV projection GEMM ----------------
// Grid (24, 32): region r = blockIdx.x>>3 picks {input, weight, bias, dst,
// scale}; 768 blocks = 3 blocks/CU (vs 1/CU when launched as 3 GEMMs).
// r=0: Qh = (q@Wq^T + bq)*0.125, head layout
// r=1: Kh =  k@Wk^T + bk,        head layout
// r=2: Vt =  v@Wv^T + bv,        transposed [bh][dk][S]
__global__ __launch_bounds__(512) void gemm_qkv(
    const float* __restrict__ q, const float* __restrict__ k, const float* __restrict__ v,
    const float* __restrict__ Wq, const float* __restrict__ Wk, const float* __restrict__ Wv,
    const float* __restrict__ bq, const float* __restrict__ bk, const float* __restrict__ bv,
    ushort* __restrict__ Qhb, ushort* __restrict__ Khb, ushort* __restrict__ Vtb)
{
  constexpr int K = D_MODEL;
  __shared__ __align__(16) ushort At[2][128 * 32];
  __shared__ __align__(16) ushort Bt[2][128 * 32];
  const int r = blockIdx.x >> 3;
  const float* A    = (r == 0) ? q  : (r == 1) ? k  : v;
  const float* W    = (r == 0) ? Wq : (r == 1) ? Wk : Wv;
  const float* bias = (r == 0) ? bq : (r == 1) ? bk : bv;
  const float outScale = (r == 0) ? 0.125f : 1.0f;

  const int tid = threadIdx.x;
  const int lane = tid & 63, wave = tid >> 6;
  const int wm = wave >> 1, wn = wave & 1;
  const int m0 = blockIdx.y * 128, n0 = (blockIdx.x & 7) * 128;
  const int row = tid >> 2, kc = tid & 3;
  const size_t aoff = (size_t)(m0 + row) * K + kc * 8;
  const size_t boff = (size_t)(n0 + row) * K + kc * 8;
  const int lchunk = (kc * 128 + row) * 8;

  bf16x8 ra = load_chunk<true>(A, aoff);
  bf16x8 rb = load_chunk<true>(W, boff);
  *(bf16x8*)&At[0][lchunk] = ra;
  *(bf16x8*)&Bt[0][lchunk] = rb;
  __syncthreads();

  f32x4 acc[2][4];
  #pragma unroll
  for (int i = 0; i < 2; ++i)
    #pragma unroll
    for (int j = 0; j < 4; ++j) acc[i][j] = (f32x4){0.f, 0.f, 0.f, 0.f};

  for (int t = 0; t < 32; ++t) {
    const int cur = t & 1;
    if (t < 31) {
      ra = load_chunk<true>(A, aoff + (size_t)(t + 1) * 32);
      rb = load_chunk<true>(W, boff + (size_t)(t + 1) * 32);
    }
    bf16x8 af[2], bfr[4];
    #pragma unroll
    for (int i = 0; i < 2; ++i)
      af[i] = *(const bf16x8*)&At[cur][((lane >> 4) * 128 + wm * 32 + i * 16 + (lane & 15)) * 8];
    #pragma unroll
    for (int j = 0; j < 4; ++j)
      bfr[j] = *(const bf16x8*)&Bt[cur][((lane >> 4) * 128 + wn * 64 + j * 16 + (lane & 15)) * 8];
    __builtin_amdgcn_s_setprio(1);
    #pragma unroll
    for (int i = 0; i < 2; ++i)
      #pragma unroll
      for (int j = 0; j < 4; ++j)
        acc[i][j] = __builtin_amdgcn_mfma_f32_16x16x32_bf16(af[i], bfr[j], acc[i][j], 0, 0, 0);
    __builtin_amdgcn_s_setprio(0);
    if (t < 31) {
      *(bf16x8*)&At[cur ^ 1][lchunk] = ra;
      *(bf16x8*)&Bt[cur ^ 1][lchunk] = rb;
    }
    __syncthreads();
  }

  #pragma unroll
  for (int i = 0; i < 2; ++i) {
    #pragma unroll
    for (int j = 0; j < 4; ++j) {
      #pragma unroll
      for (int rr = 0; rr < 4; ++rr) {
        int m = m0 + wm * 32 + i * 16 + (lane >> 4) * 4 + rr;
        int n = n0 + wn * 64 + j * 16 + (lane & 15);
        float val = (acc[i][j][rr] + bias[n]) * outScale;
        int b = m >> 11, s = m & (SEQ - 1);
        int h = n >> 6,  d = n & (DK - 1);
        if (r == 0)
          Qhb[((size_t)(b * NHEAD + h) * SEQ + s) * DK + d] = f2bf(val);
        else if (r == 1)
          Khb[((size_t)(b * NHEAD + h) * SEQ + s) * DK + d] = f2bf(val);
        else
          Vtb[((size_t)(b * NHEAD + h) * DK + d) * SEQ + s] = f2bf(val);
      }
    }
  }
}

// ---------------- Output GEMM: out = ctx @ Wo^T + bo (fp32 out) ----------------
__global__ __launch_bounds__(512) void gemm_out(
    const ushort* __restrict__ A, const float* __restrict__ B,
    const float* __restrict__ bias, float* __restrict__ C,
    int M, int N, int K)
{
  __shared__ __align__(16) ushort At[2][128 * 32];
  __shared__ __align__(16) ushort Bt[2][128 * 32];
  const int tid = threadIdx.x;
  const int lane = tid & 63, wave = tid >> 6;
  const int wm = wave >> 1, wn = wave & 1;
  const int m0 = blockIdx.y * 128, n0 = blockIdx.x * 128;
  const int row = tid >> 2, kc = tid & 3;
  const size_t aoff = (size_t)(m0 + row) * K + kc * 8;
  const size_t boff = (size_t)(n0 + row) * K + kc * 8;
  const int lchunk = (kc * 128 + row) * 8;

  bf16x8 ra = load_chunk<false>(A, aoff);
  bf16x8 rb = load_chunk<true>(B, boff);
  *(bf16x8*)&At[0][lchunk] = ra;
  *(bf16x8*)&Bt[0][lchunk] = rb;
  __syncthreads();

  f32x4 acc[2][4];
  #pragma unroll
  for (int i = 0; i < 2; ++i)
    #pragma unroll
    for (int j = 0; j < 4; ++j) acc[i][j] = (f32x4){0.f, 0.f, 0.f, 0.f};

  for (int t = 0; t < 32; ++t) {
    const int cur = t & 1;
    if (t < 31) {
      ra = load_chunk<false>(A, aoff + (size_t)(t + 1) * 32);
      rb = load_chunk<true>(B, boff + (size_t)(t + 1) * 32);
    }
    bf16x8 af[2], bfr[4];
    #pragma unroll
    for (int i = 0; i < 2; ++i)
      af[i] = *(const bf16x8*)&At[cur][((lane >> 4) * 128 + wm * 32 + i * 16 + (lane & 15)) * 8];
    #pragma unroll
    for (int j = 0; j < 4; ++j)
      bfr[j] = *(const bf16x8*)&Bt[cur][((lane >> 4) * 128 + wn * 64 + j * 16 + (lane & 15)) * 8];
    __builtin_amdgcn_s_setprio(1);
    #pragma unroll
    for (int i = 0; i < 2; ++i)
      #pragma unroll
      for (int j = 0; j < 4; ++j)
        acc[i][j] = __builtin_amdgcn_mfma_f32_16x16x32_bf16(af[i], bfr[j], acc[i][j], 0, 0, 0);
    __builtin_amdgcn_s_setprio(0);
    if (t < 31) {
      *(bf16x8*)&At[cur ^ 1][lchunk] = ra;
      *(bf16x8*)&Bt[cur ^ 1][lchunk] = rb;
    }
    __syncthreads();
  }

  #pragma unroll
  for (int i = 0; i < 2; ++i) {
    #pragma unroll
    for (int j = 0; j < 4; ++j) {
      #pragma unroll
      for (int r = 0; r < 4; ++r) {
        int m = m0 + wm * 32 + i * 16 + (lane >> 4) * 4 + r;
        int n = n0 + wn * 64 + j * 16 + (lane & 15);
        C[(size_t)m * N + n] = acc[i][j][r] + bias[n];
      }
    }
  }
}

// ---------------- attn pass A: row sums -> inv (no LDS tiles, high occupancy) ----------------
// One block = 64 q-rows of one (b,h); 4 waves; wave w owns keys [w*512,+512).
// Math/order identical to R10 pass A (absmax-stable).
__global__ __launch_bounds__(256) void attn_sums(
    const ushort* __restrict__ Qh, const ushort* __restrict__ Kh,
    float* __restrict__ rinv)
{
  __shared__ float sRed[4][64];
  const int tid = threadIdx.x, lane = tid & 63, wave = tid >> 6;
  const int l16 = lane & 15, lq = lane >> 4;
  const int bid  = blockIdx.x;
  const int sbid = (bid & 7) * 128 + (bid >> 3);   // XCD swizzle (1024 = 8*128)
  const int bh = sbid >> 5;
  const int q0 = (sbid & 31) * 64;
  const ushort* Qp = Qh + ((size_t)bh * SEQ + q0) * DK;
  const ushort* Kp = Kh + (size_t)bh * SEQ * DK;

  bf16x8 bq[4][2];
  #pragma unroll
  for (int qg = 0; qg < 4; ++qg) {
    bq[qg][0] = *(const bf16x8*)(Qp + (qg * 16 + l16) * DK + lq * 8);
    bq[qg][1] = *(const bf16x8*)(Qp + (qg * 16 + l16) * DK + 32 + lq * 8);
  }
  const int wkey0 = wave * 512;
  const ushort* kbase = Kp + (size_t)(wkey0 + l16) * DK + lq * 8;

  float lsum[4] = {0.f, 0.f, 0.f, 0.f};
  bf16x8 kb[2][8];
  #pragma unroll
  for (int ni = 0; ni < 4; ++ni) {
    kb[0][2 * ni]     = *(const bf16x8*)(kbase + (size_t)ni * 16 * DK);
    kb[0][2 * ni + 1] = *(const bf16x8*)(kbase + (size_t)ni * 16 * DK + 32);
  }
  for (int kt = 0; kt < 8; ++kt) {
    const int cb = kt & 1;
    if (kt < 7) {
      const ushort* kn = kbase + (size_t)(kt + 1) * 64 * DK;
      #pragma unroll
      for (int ni = 0; ni < 4; ++ni) {
        kb[cb ^ 1][2 * ni]     = *(const bf16x8*)(kn + (size_t)ni * 16 * DK);
        kb[cb ^ 1][2 * ni + 1] = *(const bf16x8*)(kn + (size_t)ni * 16 * DK + 32);
      }
    }
    #pragma unroll
    for (int ni = 0; ni < 4; ++ni) {
      f32x4 acc[4];
      __builtin_amdgcn_s_setprio(1);
      #pragma unroll
      for (int qg = 0; qg < 4; ++qg) {
        acc[qg] = (f32x4){0.f, 0.f, 0.f, 0.f};
        acc[qg] = __builtin_amdgcn_mfma_f32_16x16x32_bf16(kb[cb][2 * ni],     bq[qg][0], acc[qg], 0, 0, 0);
        acc[qg] = __builtin_amdgcn_mfma_f32_16x16x32_bf16(kb[cb][2 * ni + 1], bq[qg][1], acc[qg], 0, 0, 0);
      }
      __builtin_amdgcn_s_setprio(0);
      #pragma unroll
      for (int qg = 0; qg < 4; ++qg)
        lsum[qg] += (__expf(acc[qg][0]) + __expf(acc[qg][1]))
                  + (__expf(acc[qg][2]) + __expf(acc[qg][3]));
    }
  }
  #pragma unroll
  for (int qg = 0; qg < 4; ++qg) {
    float v = lsum[qg];
    v += __shfl_xor(v, 16);
    v += __shfl_xor(v, 32);
    if (lane < 16) sRed[wave][qg * 16 + lane] = v;
  }
  __syncthreads();
  if (tid < 64)
    rinv[(size_t)bh * SEQ + q0 + tid] =
        1.0f / (sRed[0][tid] + sRed[1][tid] + sRed[2][tid] + sRed[3][tid]);
}

// ---------------- attn pass B: emit attn + PV (R10 pass B, inv from global) ----------------
__global__ __launch_bounds__(256, 2) void attn_emit(
    const ushort* __restrict__ Qh, const ushort* __restrict__ Kh,
    const ushort* __restrict__ Vt, const float* __restrict__ rinv,
    float* __restrict__ attn, ushort* __restrict__ ctxb)
{
  __shared__ __align__(16) ushort sT[4][64 * 64];   // 4 x 8KB wave-private tiles
  __shared__ float sInv[64];

  const int tid = threadIdx.x, lane = tid & 63, wave = tid >> 6;
  const int l16 = lane & 15, lq = lane >> 4;
  const int bid  = blockIdx.x;
  const int sbid = (bid & 7) * 128 + (bid >> 3);   // XCD swizzle (1024 = 8*128)
  const int bh = sbid >> 5;
  const int q0 = (sbid & 31) * 64;
  const ushort* Qp = Qh + ((size_t)bh * SEQ + q0) * DK;
  const ushort* Kp = Kh + (size_t)bh * SEQ * DK;
  const ushort* Vp = Vt + (size_t)bh * DK * SEQ;

  if (tid < 64) sInv[tid] = rinv[(size_t)bh * SEQ + q0 + tid];

  bf16x8 bq[4][2];
  #pragma unroll
  for (int qg = 0; qg < 4; ++qg) {
    bq[qg][0] = *(const bf16x8*)(Qp + (qg * 16 + l16) * DK + lq * 8);
    bq[qg][1] = *(const bf16x8*)(Qp + (qg * 16 + l16) * DK + 32 + lq * 8);
  }
  const int wkey0 = wave * 512;
  const ushort* kbase = Kp + (size_t)(wkey0 + l16) * DK + lq * 8;
  __syncthreads();   // sInv ready

  ushort* tile = sT[wave];
  const ushort* vbase = Vp + (size_t)l16 * SEQ + wkey0 + lq * 8;
  f32x4 cacc[4][4];
  #pragma unroll
  for (int qg = 0; qg < 4; ++qg)
    #pragma unroll
    for (int ni = 0; ni < 4; ++ni) cacc[qg][ni] = (f32x4){0.f, 0.f, 0.f, 0.f};

  bf16x8 kb[2][8];
  #pragma unroll
  for (int ni = 0; ni < 4; ++ni) {
    kb[0][2 * ni]     = *(const bf16x8*)(kbase + (size_t)ni * 16 * DK);
    kb[0][2 * ni + 1] = *(const bf16x8*)(kbase + (size_t)ni * 16 * DK + 32);
  }

  for (int kt = 0; kt < 8; ++kt) {
    const int cb = kt & 1;
    bf16x8 vb[2][4];
    #pragma unroll
    for (int h = 0; h < 2; ++h)
      #pragma unroll
      for (int ni = 0; ni < 4; ++ni)
        vb[h][ni] = *(const bf16x8*)(vbase + (size_t)ni * 16 * SEQ + kt * 64 + h * 32);
    if (kt < 7) {
      const ushort* kn = kbase + (size_t)(kt + 1) * 64 * DK;
      #pragma unroll
      for (int ni = 0; ni < 4; ++ni) {
        kb[cb ^ 1][2 * ni]     = *(const bf16x8*)(kn + (size_t)ni * 16 * DK);
        kb[cb ^ 1][2 * ni + 1] = *(const bf16x8*)(kn + (size_t)ni * 16 * DK + 32);
      }
    }
    // QK^T (swapped) + exp -> tile
    #pragma unroll
    for (int ni = 0; ni < 4; ++ni) {
      f32x4 acc[4];
      __builtin_amdgcn_s_setprio(1);
      #pragma unroll
      for (int qg = 0; qg < 4; ++qg) {
        acc[qg] = (f32x4){0.f, 0.f, 0.f, 0.f};
        acc[qg] = __builtin_amdgcn_mfma_f32_16x16x32_bf16(kb[cb][2 * ni],     bq[qg][0], acc[qg], 0, 0, 0);
        acc[qg] = __builtin_amdgcn_mfma_f32_16x16x32_bf16(kb[cb][2 * ni + 1], bq[qg][1], acc[qg], 0, 0, 0);
      }
      __builtin_amdgcn_s_setprio(0);
      #pragma unroll
      for (int qg = 0; qg < 4; ++qg) {
        float p0 = __expf(acc[qg][0]);
        float p1 = __expf(acc[qg][1]);
        float p2 = __expf(acc[qg][2]);
        float p3 = __expf(acc[qg][3]);
        ushort4 pk;
        pk.x = f2bf(p0); pk.y = f2bf(p1); pk.z = f2bf(p2); pk.w = f2bf(p3);
        const int prow = qg * 16 + l16;
        const int col = ni * 16 + lq * 4;
        *(ushort4*)&tile[prow * 64 + (((col >> 3) ^ (prow & 7)) << 3) + (col & 7)] = pk;
      }
    }
    // PV from tile
    #pragma unroll
    for (int qg = 0; qg < 4; ++qg) {
      const int prow = qg * 16 + l16;
      const int rsw = prow & 7;
      bf16x8 pa0 = *(const bf16x8*)&tile[prow * 64 + ((lq) ^ rsw) * 8];
      bf16x8 pa1 = *(const bf16x8*)&tile[prow * 64 + ((4 + lq) ^ rsw) * 8];
      __builtin_amdgcn_s_setprio(1);
      #pragma unroll
      for (int ni = 0; ni < 4; ++ni)
        cacc[qg][ni] = __builtin_amdgcn_mfma_f32_16x16x32_bf16(pa0, vb[0][ni], cacc[qg][ni], 0, 0, 0);
      #pragma unroll
      for (int ni = 0; ni < 4; ++ni)
        cacc[qg][ni] = __builtin_amdgcn_mfma_f32_16x16x32_bf16(pa1, vb[1][ni], cacc[qg][ni], 0, 0, 0);
      __builtin_amdgcn_s_setprio(0);
    }
    // normalized attn store: full-line nontemporal (4 rows x 256B per instr)
    {
      const int r4 = lane >> 4;
      const int col = (lane & 15) * 4;
      #pragma unroll
      for (int rg = 0; rg < 16; ++rg) {
        const int prow = rg * 4 + r4;
        const float iv = sInv[prow];
        const int chunk = (col >> 3) ^ (prow & 7);
        ushort4 pv = *(const ushort4*)&tile[prow * 64 + (chunk << 3) + (col & 7)];
        f32x4 o;
        o[0] = bf2f(pv.x) * iv;
        o[1] = bf2f(pv.y) * iv;
        o[2] = bf2f(pv.z) * iv;
        o[3] = bf2f(pv.w) * iv;
        float* ap = attn + ((size_t)(bh * SEQ + q0 + prow)) * SEQ + wkey0 + kt * 64 + col;
        __builtin_nontemporal_store(o, (f32x4*)ap);
      }
    }
  }

  // ctx: cross-wave reduce in two 32-row halves
  __syncthreads();
  const int bb = bh >> 4, hh = bh & 15;
  #pragma unroll
  for (int half = 0; half < 2; ++half) {
    float* ft = (float*)sT[wave];
    #pragma unroll
    for (int hg = 0; hg < 2; ++hg) {
      const int qg = half * 2 + hg;
      #pragma unroll
      for (int ni = 0; ni < 4; ++ni)
        #pragma unroll
        for (int r = 0; r < 4; ++r)
          ft[(hg * 16 + lq * 4 + r) * 64 + ni * 16 + l16] = cacc[qg][ni][r];
    }
    __syncthreads();
    {
      const int row = tid >> 3;
      const int c = (tid & 7) * 8;
      const float iv = sInv[half * 32 + row];
      float s0 = 0.f, s1 = 0.f, s2 = 0.f, s3 = 0.f, s4 = 0.f, s5 = 0.f, s6 = 0.f, s7 = 0.f;
      #pragma unroll
      for (int w = 0; w < 4; ++w) {
        const float* fw = (const float*)sT[w] + row * 64 + c;
        s0 += fw[0]; s1 += fw[1]; s2 += fw[2]; s3 += fw[3];
        s4 += fw[4]; s5 += fw[5]; s6 += fw[6]; s7 += fw[7];
      }
      bf16x8 ob;
      ob[0] = (short)f2bf(s0 * iv); ob[1] = (short)f2bf(s1 * iv);
      ob[2] = (short)f2bf(s2 * iv); ob[3] = (short)f2bf(s3 * iv);
      ob[4] = (short)f2bf(s4 * iv); ob[5] = (short)f2bf(s5 * iv);
      ob[6] = (short)f2bf(s6 * iv); ob[7] = (short)f2bf(s7 * iv);
      *(bf16x8*)(ctxb + ((size_t)(bb * SEQ + q0 + half * 32 + row)) * D_MODEL + hh * DK + c) = ob;
    }
    __syncthreads();
  }
}

extern "C" void kernel_launch(void* const* d_in, const int* in_sizes, int n_in,
                              void* d_out, int out_size, void* d_ws, size_t ws_size,
                              hipStream_t stream)
{
  const float* q  = (const float*)d_in[0];
  const float* k  = (const float*)d_in[1];
  const float* v  = (const float*)d_in[2];
  const float* Wq = (const float*)d_in[3];
  const float* bq = (const float*)d_in[4];
  const float* Wk = (const float*)d_in[5];
  const float* bk = (const float*)d_in[6];
  const float* Wv = (const float*)d_in[7];
  const float* bv = (const float*)d_in[8];
  const float* Wo = (const float*)d_in[9];
  const float* bo = (const float*)d_in[10];

  float* out  = (float*)d_out;
  float* attn = out + (size_t)BATCH * SEQ * D_MODEL;

  const size_t XEL = (size_t)BATCH * SEQ * D_MODEL;  // 4 Mi elems
  ushort* Qhb  = (ushort*)d_ws;
  ushort* Khb  = Qhb + XEL;
  ushort* Vtb  = Khb + XEL;
  ushort* ctxb = Vtb + XEL;
  float*  rinv = (float*)(ctxb + XEL);               // 256 KB

  const int M = BATCH * SEQ;
  gemm_qkv<<<dim3(24, M / 128), 512, 0, stream>>>(q, k, v, Wq, Wk, Wv, bq, bk, bv,
                                                  Qhb, Khb, Vtb);

  attn_sums<<<dim3(BATCH * NHEAD * (SEQ / 64)), 256, 0, stream>>>(Qhb, Khb, rinv);
  attn_emit<<<dim3(BATCH * NHEAD * (SEQ / 64)), 256, 0, stream>>>(Qhb, Khb, Vtb, rinv, attn, ctxb);

  gemm_out<<<dim3(D_MODEL / 128, M / 128), 512, 0, stream>>>(ctxb, Wo, bo, out, M, D_MODEL, D_MODEL);
}

// Round 12
// 244.375 us; speedup vs baseline: 2.0881x; 1.3080x over previous
//
#include <hip/hip_runtime.h>
#include <hip/hip_bf16.h>

#define D_MODEL 1024
#define NHEAD   16
#define DK      64
#define SEQ     2048
#define BATCH   2

typedef __attribute__((ext_vector_type(8))) short bf16x8;   // 8 bf16 = 4 VGPR
typedef __attribute__((ext_vector_type(4))) float f32x4;

static __device__ __forceinline__ ushort f2bf(float f) {
  union { float f; unsigned u; } x; x.f = f;
  unsigned r = x.u + 0x7FFF + ((x.u >> 16) & 1);   // round-to-nearest-even
  return (ushort)(r >> 16);
}
static __device__ __forceinline__ float bf2f(ushort b) {
  union { unsigned u; float f; } x; x.u = ((unsigned)b) << 16;
  return x.f;
}

template<bool F32>
static __device__ __forceinline__ bf16x8 load_chunk(const void* base, size_t eoff) {
  if constexpr (F32) {
    const float* p = (const float*)base + eoff;
    float4 a = *(const float4*)p;
    float4 b = *(const float4*)(p + 4);
    bf16x8 o;
    o[0] = (short)f2bf(a.x); o[1] = (short)f2bf(a.y);
    o[2] = (short)f2bf(a.z); o[3] = (short)f2bf(a.w);
    o[4] = (short)f2bf(b.x); o[5] = (short)f2bf(b.y);
    o[6] = (short)f2bf(b.z); o[7] = (short)f2bf(b.w);
    return o;
  } else {
    return *(const bf16x8*)((const ushort*)base + eoff);
  }
}

// ---------------- Fused QKV projection GEMM (as R11) ----------------
__global__ __launch_bounds__(512) void gemm_qkv(
    const float* __restrict__ q, const float* __restrict__ k, const float* __restrict__ v,
    const float* __restrict__ Wq, const float* __restrict__ Wk, const float* __restrict__ Wv,
    const float* __restrict__ bq, const float* __restrict__ bk, const float* __restrict__ bv,
    ushort* __restrict__ Qhb, ushort* __restrict__ Khb, ushort* __restrict__ Vtb)
{
  constexpr int K = D_MODEL;
  __shared__ __align__(16) ushort At[2][128 * 32];
  __shared__ __align__(16) ushort Bt[2][128 * 32];
  const int r = blockIdx.x >> 3;
  const float* A    = (r == 0) ? q  : (r == 1) ? k  : v;
  const float* W    = (r == 0) ? Wq : (r == 1) ? Wk : Wv;
  const float* bias = (r == 0) ? bq : (r == 1) ? bk : bv;
  const float outScale = (r == 0) ? 0.125f : 1.0f;

  const int tid = threadIdx.x;
  const int lane = tid & 63, wave = tid >> 6;
  const int wm = wave >> 1, wn = wave & 1;
  const int m0 = blockIdx.y * 128, n0 = (blockIdx.x & 7) * 128;
  const int row = tid >> 2, kc = tid & 3;
  const size_t aoff = (size_t)(m0 + row) * K + kc * 8;
  const size_t boff = (size_t)(n0 + row) * K + kc * 8;
  const int lchunk = (kc * 128 + row) * 8;

  bf16x8 ra = load_chunk<true>(A, aoff);
  bf16x8 rb = load_chunk<true>(W, boff);
  *(bf16x8*)&At[0][lchunk] = ra;
  *(bf16x8*)&Bt[0][lchunk] = rb;
  __syncthreads();

  f32x4 acc[2][4];
  #pragma unroll
  for (int i = 0; i < 2; ++i)
    #pragma unroll
    for (int j = 0; j < 4; ++j) acc[i][j] = (f32x4){0.f, 0.f, 0.f, 0.f};

  for (int t = 0; t < 32; ++t) {
    const int cur = t & 1;
    if (t < 31) {
      ra = load_chunk<true>(A, aoff + (size_t)(t + 1) * 32);
      rb = load_chunk<true>(W, boff + (size_t)(t + 1) * 32);
    }
    bf16x8 af[2], bfr[4];
    #pragma unroll
    for (int i = 0; i < 2; ++i)
      af[i] = *(const bf16x8*)&At[cur][((lane >> 4) * 128 + wm * 32 + i * 16 + (lane & 15)) * 8];
    #pragma unroll
    for (int j = 0; j < 4; ++j)
      bfr[j] = *(const bf16x8*)&Bt[cur][((lane >> 4) * 128 + wn * 64 + j * 16 + (lane & 15)) * 8];
    __builtin_amdgcn_s_setprio(1);
    #pragma unroll
    for (int i = 0; i < 2; ++i)
      #pragma unroll
      for (int j = 0; j < 4; ++j)
        acc[i][j] = __builtin_amdgcn_mfma_f32_16x16x32_bf16(af[i], bfr[j], acc[i][j], 0, 0, 0);
    __builtin_amdgcn_s_setprio(0);
    if (t < 31) {
      *(bf16x8*)&At[cur ^ 1][lchunk] = ra;
      *(bf16x8*)&Bt[cur ^ 1][lchunk] = rb;
    }
    __syncthreads();
  }

  #pragma unroll
  for (int i = 0; i < 2; ++i) {
    #pragma unroll
    for (int j = 0; j < 4; ++j) {
      #pragma unroll
      for (int rr = 0; rr < 4; ++rr) {
        int m = m0 + wm * 32 + i * 16 + (lane >> 4) * 4 + rr;
        int n = n0 + wn * 64 + j * 16 + (lane & 15);
        float val = (acc[i][j][rr] + bias[n]) * outScale;
        int b = m >> 11, s = m & (SEQ - 1);
        int h = n >> 6,  d = n & (DK - 1);
        if (r == 0)
          Qhb[((size_t)(b * NHEAD + h) * SEQ + s) * DK + d] = f2bf(val);
        else if (r == 1)
          Khb[((size_t)(b * NHEAD + h) * SEQ + s) * DK + d] = f2bf(val);
        else
          Vtb[((size_t)(b * NHEAD + h) * DK + d) * SEQ + s] = f2bf(val);
      }
    }
  }
}

// ---------------- Output GEMM (as R11) ----------------
__global__ __launch_bounds__(512) void gemm_out(
    const ushort* __restrict__ A, const float* __restrict__ B,
    const float* __restrict__ bias, float* __restrict__ C,
    int M, int N, int K)
{
  __shared__ __align__(16) ushort At[2][128 * 32];
  __shared__ __align__(16) ushort Bt[2][128 * 32];
  const int tid = threadIdx.x;
  const int lane = tid & 63, wave = tid >> 6;
  const int wm = wave >> 1, wn = wave & 1;
  const int m0 = blockIdx.y * 128, n0 = blockIdx.x * 128;
  const int row = tid >> 2, kc = tid & 3;
  const size_t aoff = (size_t)(m0 + row) * K + kc * 8;
  const size_t boff = (size_t)(n0 + row) * K + kc * 8;
  const int lchunk = (kc * 128 + row) * 8;

  bf16x8 ra = load_chunk<false>(A, aoff);
  bf16x8 rb = load_chunk<true>(B, boff);
  *(bf16x8*)&At[0][lchunk] = ra;
  *(bf16x8*)&Bt[0][lchunk] = rb;
  __syncthreads();

  f32x4 acc[2][4];
  #pragma unroll
  for (int i = 0; i < 2; ++i)
    #pragma unroll
    for (int j = 0; j < 4; ++j) acc[i][j] = (f32x4){0.f, 0.f, 0.f, 0.f};

  for (int t = 0; t < 32; ++t) {
    const int cur = t & 1;
    if (t < 31) {
      ra = load_chunk<false>(A, aoff + (size_t)(t + 1) * 32);
      rb = load_chunk<true>(B, boff + (size_t)(t + 1) * 32);
    }
    bf16x8 af[2], bfr[4];
    #pragma unroll
    for (int i = 0; i < 2; ++i)
      af[i] = *(const bf16x8*)&At[cur][((lane >> 4) * 128 + wm * 32 + i * 16 + (lane & 15)) * 8];
    #pragma unroll
    for (int j = 0; j < 4; ++j)
      bfr[j] = *(const bf16x8*)&Bt[cur][((lane >> 4) * 128 + wn * 64 + j * 16 + (lane & 15)) * 8];
    __builtin_amdgcn_s_setprio(1);
    #pragma unroll
    for (int i = 0; i < 2; ++i)
      #pragma unroll
      for (int j = 0; j < 4; ++j)
        acc[i][j] = __builtin_amdgcn_mfma_f32_16x16x32_bf16(af[i], bfr[j], acc[i][j], 0, 0, 0);
    __builtin_amdgcn_s_setprio(0);
    if (t < 31) {
      *(bf16x8*)&At[cur ^ 1][lchunk] = ra;
      *(bf16x8*)&Bt[cur ^ 1][lchunk] = rb;
    }
    __syncthreads();
  }

  #pragma unroll
  for (int i = 0; i < 2; ++i) {
    #pragma unroll
    for (int j = 0; j < 4; ++j) {
      #pragma unroll
      for (int r = 0; r < 4; ++r) {
        int m = m0 + wm * 32 + i * 16 + (lane >> 4) * 4 + r;
        int n = n0 + wn * 64 + j * 16 + (lane & 15);
        C[(size_t)m * N + n] = acc[i][j][r] + bias[n];
      }
    }
  }
}

// ---------------- Fused flash-style attention, 128-row blocks ----------------
// One block = 128 q-rows of one (b,h); 512 threads / 8 waves; wave w owns
// rows [w*16, w*16+16) and iterates ALL keys in 64-key LDS tiles shared by
// all waves (K/V staged once per block per pass -> K/V L2 reads cut ~2x vs
// R11's per-wave streaming, and each staged load is 1 contiguous line).
// Pass A: QK^T -> exp -> per-wave row sums (no cross-wave reduce needed).
// Pass B: QK^T again -> wave-private P tile -> PV + full-line nontemporal
// attn stores; ctx written directly from acc (wave covers all keys).
__global__ __launch_bounds__(512, 4) void attn_fused(
    const ushort* __restrict__ Qh, const ushort* __restrict__ Kh,
    const ushort* __restrict__ Vt, float* __restrict__ attn,
    ushort* __restrict__ ctxb)
{
  __shared__ __align__(16) ushort sK[2][64 * 64];   // 2 x 8KB, XOR-swizzled
  __shared__ __align__(16) ushort sV[2][64 * 64];   // 2 x 8KB
  __shared__ __align__(16) ushort sP[8][16 * 64];   // per-wave P tiles, 16KB
  __shared__ float sInv[128];

  const int tid = threadIdx.x, lane = tid & 63, wave = tid >> 6;
  const int l16 = lane & 15, lq = lane >> 4;
  const int swz = l16 & 7;
  // XCD swizzle: 512 blocks = 8 XCDs x 64 -> 4 consecutive bh per XCD.
  const int bid  = blockIdx.x;
  const int sbid = (bid & 7) * 64 + (bid >> 3);
  const int bh = sbid >> 4;
  const int q0 = (sbid & 15) * 128;
  const ushort* Qp = Qh + ((size_t)bh * SEQ + q0) * DK;
  const ushort* Kp = Kh + (size_t)bh * SEQ * DK;
  const ushort* Vp = Vt + (size_t)bh * DK * SEQ;

  // Q B-frags for this wave's 16 rows (persistent)
  bf16x8 bq0 = *(const bf16x8*)(Qp + (wave * 16 + l16) * DK + lq * 8);
  bf16x8 bq1 = *(const bf16x8*)(Qp + (wave * 16 + l16) * DK + 32 + lq * 8);

  // staging: thread t loads one 16B chunk per matrix per tile
  const int srow = tid >> 3;                         // 0..63 (key or d)
  const int sc   = tid & 7;                          // dk/key chunk
  const int sdst = (srow * 8 + (sc ^ (srow & 7))) * 8;
  const ushort* kgsrc = Kp + (size_t)tid * 8;        // K tile kt: + kt*4096
  const ushort* vgsrc = Vp + (size_t)srow * SEQ + sc * 8;  // V tile kt: + kt*64

  // ================= Pass A: row sums =================
  float lsum = 0.f;
  {
    bf16x8 rk = *(const bf16x8*)kgsrc;
    *(bf16x8*)&sK[0][sdst] = rk;
    __syncthreads();
    for (int kt = 0; kt < 32; ++kt) {
      const int cur = kt & 1;
      if (kt < 31) rk = *(const bf16x8*)(kgsrc + (size_t)(kt + 1) * 4096);
      __builtin_amdgcn_s_setprio(1);
      #pragma unroll
      for (int ni = 0; ni < 4; ++ni) {
        bf16x8 kf0 = *(const bf16x8*)&sK[cur][((ni * 16 + l16) * 8 + (lq ^ swz)) * 8];
        bf16x8 kf1 = *(const bf16x8*)&sK[cur][((ni * 16 + l16) * 8 + ((4 + lq) ^ swz)) * 8];
        f32x4 acc = (f32x4){0.f, 0.f, 0.f, 0.f};
        acc = __builtin_amdgcn_mfma_f32_16x16x32_bf16(kf0, bq0, acc, 0, 0, 0);
        acc = __builtin_amdgcn_mfma_f32_16x16x32_bf16(kf1, bq1, acc, 0, 0, 0);
        lsum += (__expf(acc[0]) + __expf(acc[1])) + (__expf(acc[2]) + __expf(acc[3]));
      }
      __builtin_amdgcn_s_setprio(0);
      if (kt < 31) *(bf16x8*)&sK[cur ^ 1][sdst] = rk;
      __syncthreads();
    }
  }
  lsum += __shfl_xor(lsum, 16);
  lsum += __shfl_xor(lsum, 32);
  if (lane < 16) sInv[wave * 16 + lane] = 1.0f / lsum;  // own-wave use only

  // ================= Pass B: attn emit + PV =================
  f32x4 cacc[4];
  #pragma unroll
  for (int ni = 0; ni < 4; ++ni) cacc[ni] = (f32x4){0.f, 0.f, 0.f, 0.f};
  ushort* myP = sP[wave];
  {
    bf16x8 rk = *(const bf16x8*)kgsrc;
    bf16x8 rv = *(const bf16x8*)vgsrc;
    __syncthreads();                 // all pass-A reads of sK done
    *(bf16x8*)&sK[0][sdst] = rk;
    *(bf16x8*)&sV[0][sdst] = rv;
    __syncthreads();
    for (int kt = 0; kt < 32; ++kt) {
      const int cur = kt & 1;
      if (kt < 31) {
        rk = *(const bf16x8*)(kgsrc + (size_t)(kt + 1) * 4096);
        rv = *(const bf16x8*)(vgsrc + (size_t)(kt + 1) * 64);
      }
      // QK^T + exp -> wave-private P tile
      __builtin_amdgcn_s_setprio(1);
      #pragma unroll
      for (int ni = 0; ni < 4; ++ni) {
        bf16x8 kf0 = *(const bf16x8*)&sK[cur][((ni * 16 + l16) * 8 + (lq ^ swz)) * 8];
        bf16x8 kf1 = *(const bf16x8*)&sK[cur][((ni * 16 + l16) * 8 + ((4 + lq) ^ swz)) * 8];
        f32x4 acc = (f32x4){0.f, 0.f, 0.f, 0.f};
        acc = __builtin_amdgcn_mfma_f32_16x16x32_bf16(kf0, bq0, acc, 0, 0, 0);
        acc = __builtin_amdgcn_mfma_f32_16x16x32_bf16(kf1, bq1, acc, 0, 0, 0);
        ushort4 pk;
        pk.x = f2bf(__expf(acc[0]));
        pk.y = f2bf(__expf(acc[1]));
        pk.z = f2bf(__expf(acc[2]));
        pk.w = f2bf(__expf(acc[3]));
        const int col = ni * 16 + lq * 4;
        *(ushort4*)&myP[(l16 * 8 + ((col >> 3) ^ swz)) * 8 + (col & 7)] = pk;
      }
      // PV from P tile + V tile
      #pragma unroll
      for (int h = 0; h < 2; ++h) {
        bf16x8 pa = *(const bf16x8*)&myP[(l16 * 8 + ((h * 4 + lq) ^ swz)) * 8];
        #pragma unroll
        for (int ni = 0; ni < 4; ++ni) {
          bf16x8 vf = *(const bf16x8*)&sV[cur][((ni * 16 + l16) * 8 + ((h * 4 + lq) ^ swz)) * 8];
          cacc[ni] = __builtin_amdgcn_mfma_f32_16x16x32_bf16(pa, vf, cacc[ni], 0, 0, 0);
        }
      }
      __builtin_amdgcn_s_setprio(0);
      // stage next tile (writes to the buffer no one reads this iteration)
      if (kt < 31) {
        *(bf16x8*)&sK[cur ^ 1][sdst] = rk;
        *(bf16x8*)&sV[cur ^ 1][sdst] = rv;
      }
      // attn store: full-line nontemporal, wave's 16 rows x 64 keys
      {
        const int r4 = lane >> 4, c16 = lane & 15;
        const int col = c16 * 4;
        #pragma unroll
        for (int rg = 0; rg < 4; ++rg) {
          const int pr = rg * 4 + r4;
          const float iv = sInv[wave * 16 + pr];
          ushort4 pv = *(const ushort4*)&myP[(pr * 8 + ((col >> 3) ^ (pr & 7))) * 8 + (col & 7)];
          f32x4 o;
          o[0] = bf2f(pv.x) * iv;
          o[1] = bf2f(pv.y) * iv;
          o[2] = bf2f(pv.z) * iv;
          o[3] = bf2f(pv.w) * iv;
          float* ap = attn + ((size_t)(bh * SEQ + q0 + wave * 16 + pr)) * SEQ + kt * 64 + col;
          __builtin_nontemporal_store(o, (f32x4*)ap);
        }
      }
      __syncthreads();
    }
  }

  // ctx write: wave covers all keys -> acc complete, no cross-wave reduce
  const int bb = bh >> 4, hh = bh & 15;
  #pragma unroll
  for (int ni = 0; ni < 4; ++ni) {
    #pragma unroll
    for (int r = 0; r < 4; ++r) {
      const int qrow = wave * 16 + lq * 4 + r;
      const float iv = sInv[qrow];
      ctxb[((size_t)(bb * SEQ + q0 + qrow)) * D_MODEL + hh * DK + ni * 16 + l16] =
          f2bf(cacc[ni][r] * iv);
    }
  }
}

extern "C" void kernel_launch(void* const* d_in, const int* in_sizes, int n_in,
                              void* d_out, int out_size, void* d_ws, size_t ws_size,
                              hipStream_t stream)
{
  const float* q  = (const float*)d_in[0];
  const float* k  = (const float*)d_in[1];
  const float* v  = (const float*)d_in[2];
  const float* Wq = (const float*)d_in[3];
  const float* bq = (const float*)d_in[4];
  const float* Wk = (const float*)d_in[5];
  const float* bk = (const float*)d_in[6];
  const float* Wv = (const float*)d_in[7];
  const float* bv = (const float*)d_in[8];
  const float* Wo = (const float*)d_in[9];
  const float* bo = (const float*)d_in[10];

  float* out  = (float*)d_out;
  float* attn = out + (size_t)BATCH * SEQ * D_MODEL;

  const size_t XEL = (size_t)BATCH * SEQ * D_MODEL;  // 4 Mi elems
  ushort* Qhb  = (ushort*)d_ws;
  ushort* Khb  = Qhb + XEL;
  ushort* Vtb  = Khb + XEL;
  ushort* ctxb = Vtb + XEL;   // 32 MiB total

  const int M = BATCH * SEQ;
  gemm_qkv<<<dim3(24, M / 128), 512, 0, stream>>>(q, k, v, Wq, Wk, Wv, bq, bk, bv,
                                                  Qhb, Khb, Vtb);

  attn_fused<<<dim3(BATCH * NHEAD * (SEQ / 128)), 512, 0, stream>>>(Qhb, Khb, Vtb, attn, ctxb);

  gemm_out<<<dim3(D_MODEL / 128, M / 128), 512, 0, stream>>>(ctxb, Wo, bo, out, M, D_MODEL, D_MODEL);
}